// Round 4
// baseline (778.956 us; speedup 1.0000x reference)
//
#include <hip/hip_runtime.h>
#include <math.h>

static constexpr int BTOT = 32768;
static constexpr int IND  = 64;
static constexpr int HD   = 256;
static constexpr int LT   = 32;
static constexpr int NCH  = 8;
static constexpr int NCD  = 256;
static constexpr int TM   = 16;          // rows per block (was 32): grid 2048 -> 8 blocks/CU supply
static constexpr int NBLK = BTOT / TM;   // 2048

// workspace float offsets
static constexpr int WS_M    = 0;        // 8*256 folded score matrix M = cq@Wk
static constexpr int WS_C0   = 2048;     // 8 folded score bias c0 = cq@bk
static constexpr int WS_CSQ  = 2056;     // 8*256 codebook squared norms
static constexpr int WS_PART = 4104;     // NBLK loss partials (2048)

// output float offsets
static constexpr long long O_KCHART = 0;
static constexpr long long O_KCODE  = 32768;
static constexpr long long O_ZN     = 65536;
static constexpr long long O_ZTEX   = 1114112;
static constexpr long long O_RW     = 2162688;
static constexpr long long O_ZGEO   = 2424832;
static constexpr long long O_VQ     = 3473408;
static constexpr long long O_IDX    = 3473409;
static constexpr long long O_ZNALL  = 3735553;

// Kernel A LDS: h 4096 | x 1024 | W-panel 16 rows x 33 f4 = 2112 -> 7232 floats = 28.25 KB
// -> 5 blocks/CU. W1/W2 are staged through the panel with COALESCED loads (the round-3
// bottleneck was 64-distinct-line scattered W reads: ~260K lines/CU on the vector-memory path).
static constexpr int AL_H   = 0;
static constexpr int AL_X   = 4096;
static constexpr int AL_PAN = 5120;
static constexpr int ALDS_F = 7232;

// Kernel B LDS: 2304 floats = 9 KB -> VGPR-bound occupancy (target 7-8 blocks/CU).
static constexpr int BV    = 0;     // 16 rows x stride 36 (plain quads; +32 holds vsq)
static constexpr int BW1   = 576;   // 16 x 36: Ws1
static constexpr int BW2T  = 1152;  // 16 x 36: Ws2 transposed
static constexpr int BB1   = 1728;  // 16
static constexpr int BB2   = 1744;  // 32
static constexpr int BSCR  = 1776;  // 2 x (16 rows x 4 quarters) float4 = 512
static constexpr int BMISC = 2288;  // 16
static constexpr int BLDS_F= 2304;

typedef __attribute__((ext_vector_type(8))) __bf16 bf16x8;
typedef __attribute__((ext_vector_type(4))) float  f32x4;

__device__ __forceinline__ float gelu_f(float x) {
    return 0.5f * x * (1.0f + erff(x * 0.70710678118654752f));
}
__device__ __forceinline__ float dot4(float4 a, float4 b) {
    return a.x * b.x + a.y * b.y + a.z * b.z + a.w * b.w;
}
// numpy pairwise_sum of squares, n=32
__device__ __forceinline__ float np_sumsq32(const float* a) {
#pragma clang fp contract(off)
    float r0 = a[0]*a[0],  r1 = a[1]*a[1],  r2 = a[2]*a[2],  r3 = a[3]*a[3];
    float r4 = a[4]*a[4],  r5 = a[5]*a[5],  r6 = a[6]*a[6],  r7 = a[7]*a[7];
    r0 += a[8]*a[8];   r1 += a[9]*a[9];   r2 += a[10]*a[10]; r3 += a[11]*a[11];
    r4 += a[12]*a[12]; r5 += a[13]*a[13]; r6 += a[14]*a[14]; r7 += a[15]*a[15];
    r0 += a[16]*a[16]; r1 += a[17]*a[17]; r2 += a[18]*a[18]; r3 += a[19]*a[19];
    r4 += a[20]*a[20]; r5 += a[21]*a[21]; r6 += a[22]*a[22]; r7 += a[23]*a[23];
    r0 += a[24]*a[24]; r1 += a[25]*a[25]; r2 += a[26]*a[26]; r3 += a[27]*a[27];
    r4 += a[28]*a[28]; r5 += a[29]*a[29]; r6 += a[30]*a[30]; r7 += a[31]*a[31];
    return ((r0 + r1) + (r2 + r3)) + ((r4 + r5) + (r6 + r7));
}

// hi/lo bf16 split (approx scan only; exact fp32/fp64 re-eval unchanged)
__device__ __forceinline__ void split8(const float* f, bf16x8& hi, bf16x8& lo) {
    union U { unsigned short u[8]; bf16x8 v; };
    U h, l;
#pragma unroll
    for (int i = 0; i < 8; ++i) {
        const unsigned uf = __float_as_uint(f[i]);
        const float fl = f[i] - __uint_as_float(uf & 0xFFFF0000u);
        h.u[i] = (unsigned short)(uf >> 16);
        l.u[i] = (unsigned short)(__float_as_uint(fl) >> 16);
    }
    hi = h.v; lo = l.v;
}

// top-2 merge of two (best,2nd) pairs with (value,index) order
__device__ __forceinline__ void merge2(float& m1, float& m2, int& j1, int& j2,
                                       float o1, float o2, int p1, int p2) {
    if (o1 < m1 || (o1 == m1 && p1 < j1)) {
        float nb2; int ni2;
        if (m1 < o2 || (m1 == o2 && j1 < p2)) { nb2 = m1; ni2 = j1; }
        else                                   { nb2 = o2; ni2 = p2; }
        m1 = o1; j1 = p1; m2 = nb2; j2 = ni2;
    } else if (o1 < m2 || (o1 == m2 && p1 < j2)) {
        m2 = o1; j2 = p1;
    }
}

// ---------- prep (16 blocks) ----------
__global__ __launch_bounds__(256) void prep_kernel(
    const float* __restrict__ Wk, const float* __restrict__ bk,
    const float* __restrict__ cq, const float* __restrict__ cb,
    float* __restrict__ ws)
{
    const int g = blockIdx.x;
    const int t = threadIdx.x;
    if (g < 8) {
        float acc = 0.f;
        for (int o = 0; o < HD; ++o)
            acc += cq[g * HD + o] * Wk[o * HD + t];
        ws[WS_M + g * HD + t] = acc;
    } else {
        const int gg = g - 8;
        {
            const float* p = cb + (long long)((gg << 8) + t) * LT;
            float a[32];
#pragma unroll
            for (int d = 0; d < LT; ++d) a[d] = p[d];
            ws[WS_CSQ + (gg << 8) + t] = np_sumsq32(a);
        }
        {
            float p = cq[gg * HD + t] * bk[t];
#pragma unroll
            for (int off = 1; off < 64; off <<= 1) p += __shfl_xor(p, off, 64);
            __shared__ float red[4];
            if ((t & 63) == 0) red[t >> 6] = p;
            __syncthreads();
            if (t == 0) ws[WS_C0 + gg] = red[0] + red[1] + red[2] + red[3];
        }
    }
}

// ---------- kernel A: GEMMs (LDS-staged W panels) + routing + v ----------
__global__ __launch_bounds__(256) void main_kernel(
    const float* __restrict__ x,  const float* __restrict__ W1, const float* __restrict__ b1,
    const float* __restrict__ W2, const float* __restrict__ b2,
    const float* __restrict__ Wv, const float* __restrict__ bv,
    const float* __restrict__ ws, float* __restrict__ out)
{
    __shared__ float lds[ALDS_F];
    const int tid = threadIdx.x;
    const int bid = blockIdx.x;
    const int r0  = bid * TM;
    const int r   = tid >> 4;       // 0..15 (row)
    const int u   = tid & 15;       // 0..15 (output-col within panel / lane role)
    const int rk  = r & 7;          // h-tile xor key
    float4* pan = (float4*)&lds[AL_PAN];
    const float4* W1f = (const float4*)W1;
    const float4* W2f = (const float4*)W2;

    // stage x tile (plain, contiguous copy: 16 rows x 16 f4)
    ((float4*)&lds[AL_X])[tid] = ((const float4*)(x + (long long)r0 * IND))[tid];

    // ---- GEMM1: h1 = gelu(x @ W1^T + b1); W1 via 16-row coalesced panels ----
    for (int p = 0; p < 16; ++p) {
        __syncthreads();            // previous panel consumers (and x stage) done
        {
            const int row = tid >> 4, k4 = tid & 15;
            pan[row * 33 + k4] = W1f[(16 * p + row) * 16 + k4];
        }
        __syncthreads();
        float a = 0.f;
        for (int k4 = 0; k4 < 16; ++k4) {           // k ascending: bit-identical order
            float4 xv = *(const float4*)&lds[AL_X + r * IND + 4 * k4];
            float4 wv = pan[u * 33 + k4];
            a += dot4(xv, wv);
        }
        const int o = 16 * p + u;
        lds[AL_H + r * HD + 4 * ((o >> 2) ^ rk) + (o & 3)] = gelu_f(a + b1[o]);
    }

    // ---- GEMM2: h2 = gelu(h1 @ W2^T + b2); W2 via 16-row x half-K panels ----
    float h2v[16];
#pragma unroll
    for (int p = 0; p < 16; ++p) {
        float a = 0.f;
#pragma unroll
        for (int c = 0; c < 2; ++c) {
            __syncthreads();        // previous chunk consumers done (also orders h1 writes)
#pragma unroll
            for (int i2 = 0; i2 < 2; ++i2) {
                const int idx = tid + 256 * i2;
                const int row = idx >> 5, k4 = idx & 31;
                pan[row * 33 + k4] = W2f[(16 * p + row) * 64 + 32 * c + k4];
            }
            __syncthreads();
            for (int k4 = 0; k4 < 32; ++k4) {       // global k = 32c+k4, ascending
                float4 hv = *(const float4*)&lds[AL_H + r * HD + 4 * ((32 * c + k4) ^ rk)];
                float4 wv = pan[u * 33 + k4];
                a += dot4(hv, wv);
            }
        }
        h2v[p] = gelu_f(a + b2[16 * p + u]);
    }
    __syncthreads();                // all h1 reads done before overwrite
#pragma unroll
    for (int p = 0; p < 16; ++p) {
        const int o = 16 * p + u;
        lds[AL_H + r * HD + 4 * ((o >> 2) ^ rk) + (o & 3)] = h2v[p];
    }
    __syncthreads();

    // ---- phase 3: scores (folded M) + v; full-K per lane (duplicated across halves
    //      so v/scores stay bit-identical to the passing kernel) ----
    const int s = u & 7;
    const long long b = r0 + r;
    float  accS = 0.f;
    float4 accV; accV.x = accV.y = accV.z = accV.w = 0.f;
    const float* Mrow = ws + WS_M + s * HD;
    for (int k4 = 0; k4 < 64; ++k4) {
        float4 hv = *(const float4*)&lds[AL_H + r * HD + 4 * (k4 ^ rk)];
        float4 mv = *(const float4*)&Mrow[4 * k4];
        accS += dot4(hv, mv);
        float4 q0 = *(const float4*)&Wv[(4 * s + 0) * HD + 4 * k4];
        float4 q1 = *(const float4*)&Wv[(4 * s + 1) * HD + 4 * k4];
        float4 q2 = *(const float4*)&Wv[(4 * s + 2) * HD + 4 * k4];
        float4 q3 = *(const float4*)&Wv[(4 * s + 3) * HD + 4 * k4];
        accV.x += dot4(hv, q0);
        accV.y += dot4(hv, q1);
        accV.z += dot4(hv, q2);
        accV.w += dot4(hv, q3);
    }

    if (u < 8) {
        float4 bb = *(const float4*)&bv[4 * s];
        float4 vv;
        vv.x = accV.x + bb.x; vv.y = accV.y + bb.y;
        vv.z = accV.z + bb.z; vv.w = accV.w + bb.w;
        *(float4*)&out[O_ZTEX + b * 32 + 4 * s] = vv;   // v staging for chart_kernel
    }

    float score = (accS + ws[WS_C0 + s]) * (1.0f / 16.0f);
    float mx = score;
    mx = fmaxf(mx, __shfl_xor(mx, 1, 64));
    mx = fmaxf(mx, __shfl_xor(mx, 2, 64));
    mx = fmaxf(mx, __shfl_xor(mx, 4, 64));
    float e = expf(score - mx);
    float sm = e;
    sm += __shfl_xor(sm, 1, 64);
    sm += __shfl_xor(sm, 2, 64);
    sm += __shfl_xor(sm, 4, 64);
    if (u < 8) out[O_RW + b * 8 + s] = e / sm;
    float av = e; int ai = s;
    {
        float ov; int oi;
        ov = __shfl_xor(av, 1, 64); oi = __shfl_xor(ai, 1, 64);
        if (ov > av || (ov == av && oi < ai)) { av = ov; ai = oi; }
        ov = __shfl_xor(av, 2, 64); oi = __shfl_xor(ai, 2, 64);
        if (ov > av || (ov == av && oi < ai)) { av = ov; ai = oi; }
        ov = __shfl_xor(av, 4, 64); oi = __shfl_xor(ai, 4, 64);
        if (ov > av || (ov == av && oi < ai)) { av = ov; ai = oi; }
    }
    if (u == 0) out[O_KCHART + b] = (float)ai;
}

// ---------- kernel B: VQ chart loop (16 rows/block, tiny LDS, high occupancy) ----------
__global__ __launch_bounds__(256) void chart_kernel(
    const float* __restrict__ cb,
    const float* __restrict__ Ws1, const float* __restrict__ bs1,
    const float* __restrict__ Ws2, const float* __restrict__ bs2,
    const float* __restrict__ ws, float* __restrict__ out, float* __restrict__ wspart)
{
    __shared__ float lds[BLDS_F];
    const int tid = threadIdx.x;
    const int bid = blockIdx.x;
    const int r0  = bid * TM;
    const int r   = tid >> 4;       // 0..15
    const int u   = tid & 15;       // 0..15
    const int sq  = u & 7;          // quad index (duplicated across halves)
    const long long b = r0 + r;

    // ---- stage s-net weights + V tile ----
#pragma unroll
    for (int it = 0; it < 2; ++it) {
        int idx = tid + 256 * it;
        lds[BW1  + (idx >> 5) * 36 + (idx & 31)] = Ws1[idx];
        lds[BW2T + (idx & 15) * 36 + (idx >> 4)] = Ws2[idx];
    }
    if (tid < 16) lds[BB1 + tid] = bs1[tid];
    if (tid < 32) lds[BB2 + tid] = bs2[tid];
    const float4 vs = *(const float4*)&out[O_ZTEX + b * 32 + 4 * sq];
    if (u < 8) *(float4*)&lds[BV + r * 36 + 4 * sq] = vs;
    const float w_reg = out[O_RW + b * 8 + sq];
    const int kchart  = (int)out[O_KCHART + b];
    __syncthreads();

    // vsq per row (same np_sumsq32 tree -> same bits)
    if (u == 0) {
        float vr[32];
#pragma unroll
        for (int q = 0; q < 8; ++q) {
            float4 t4 = *(const float4*)&lds[BV + r * 36 + 4 * q];
            vr[4 * q + 0] = t4.x; vr[4 * q + 1] = t4.y;
            vr[4 * q + 2] = t4.z; vr[4 * q + 3] = t4.w;
        }
        lds[BV + r * 36 + 32] = np_sumsq32(vr);
    }

    // MFMA A-fragments (V hi/lo): row = lane&15, k-slice 8*(lane>>4)
    const int lane = tid & 63;
    const int hw   = tid >> 6;      // wave = code quarter 0..3
    const int lcol = lane & 15;
    const int lks  = lane >> 4;
    bf16x8 ahf, alf;
    {
        float f[8];
        *(float4*)&f[0] = *(const float4*)&lds[BV + lcol * 36 + 8 * lks];
        *(float4*)&f[4] = *(const float4*)&lds[BV + lcol * 36 + 8 * lks + 4];
        split8(f, ahf, alf);
    }
    __syncthreads();
    const float vsq32 = lds[BV + r * 36 + 32];

    float4 zqb; zqb.x = zqb.y = zqb.z = zqb.w = 0.f;
    float4 zn4; zn4.x = zn4.y = zn4.z = zn4.w = 0.f;
    float lossAcc = 0.f;
    int kcode = 0;

    for (int n = 0; n < NCH; ++n) {
        const float* cbn  = cb + (long long)n * (NCD * LT);
        const float* csqA = ws + WS_CSQ + (n << 8);

        // ---- MFMA approx scan over this wave's 64-code quarter ----
        float tb1[4], tb2[4]; int ti1[4], ti2[4];
#pragma unroll
        for (int j = 0; j < 4; ++j) { tb1[j] = 3.4e38f; tb2[j] = 3.4e38f; ti1[j] = 0; ti2[j] = 0; }
        const float* bbase = cbn + (64 * hw + lcol) * LT + 8 * lks;
        const float* csqn  = csqA + 64 * hw + lcol;
#pragma unroll
        for (int t = 0; t < 4; ++t) {
            float bfv[8];
            *(float4*)&bfv[0] = *(const float4*)(bbase + t * (16 * LT));
            *(float4*)&bfv[4] = *(const float4*)(bbase + t * (16 * LT) + 4);
            bf16x8 bh, bl; split8(bfv, bh, bl);
            f32x4 ac = {0.f, 0.f, 0.f, 0.f};
            ac = __builtin_amdgcn_mfma_f32_16x16x32_bf16(ahf, bh, ac, 0, 0, 0);
            ac = __builtin_amdgcn_mfma_f32_16x16x32_bf16(alf, bh, ac, 0, 0, 0);
            ac = __builtin_amdgcn_mfma_f32_16x16x32_bf16(ahf, bl, ac, 0, 0, 0);
            const float cs = csqn[t * 16];
            const int Ct = 64 * hw + 16 * t + lcol;
#pragma unroll
            for (int j = 0; j < 4; ++j) {
                float d = cs - 2.0f * ac[j];
                if (d < tb1[j])      { tb2[j] = tb1[j]; ti2[j] = ti1[j]; tb1[j] = d; ti1[j] = Ct; }
                else if (d < tb2[j]) { tb2[j] = d; ti2[j] = Ct; }
            }
        }
        // cross-lane top-2 butterfly over the 16 code-lanes
#pragma unroll
        for (int off = 1; off < 16; off <<= 1) {
#pragma unroll
            for (int j = 0; j < 4; ++j) {
                float o1 = __shfl_xor(tb1[j], off, 64); int oi1 = __shfl_xor(ti1[j], off, 64);
                float o2 = __shfl_xor(tb2[j], off, 64); int oi2 = __shfl_xor(ti2[j], off, 64);
                merge2(tb1[j], tb2[j], ti1[j], ti2[j], o1, o2, oi1, oi2);
            }
        }
        // per-row quarter-partials -> scratch (double-buffered; 1 barrier/chart)
        const int scb = BSCR + (n & 1) * 256;
        if (lcol == 0) {
#pragma unroll
            for (int j = 0; j < 4; ++j) {
                const int R2 = 4 * lks + j;         // C-layout row = (lane>>4)*4+reg
                float4 rec;
                rec.x = tb1[j]; rec.y = tb2[j];
                rec.z = (float)ti1[j]; rec.w = (float)ti2[j];
                *(float4*)&lds[scb + (R2 * 4 + hw) * 4] = rec;
            }
        }
        __syncthreads();

        // ---- merge 4 quarter-partials; exact re-eval (numerics unchanged) ----
        float m1, m2; int i1, i2;
        {
            float4 g = *(const float4*)&lds[scb + (r * 4 + 0) * 4];
            m1 = g.x; m2 = g.y; i1 = (int)g.z; i2 = (int)g.w;
#pragma unroll
            for (int h = 1; h < 4; ++h) {
                float4 gh = *(const float4*)&lds[scb + (r * 4 + h) * 4];
                merge2(m1, m2, i1, i2, gh.x, gh.y, (int)gh.z, (int)gh.w);
            }
        }
        int bestC;
        {
            const int cand = (u & 1) ? i2 : i1;
            double cr = 0.0;
            const float4* pc = (const float4*)(cbn + cand * LT);
#pragma unroll
            for (int j = 0; j < 8; ++j) {
                float4 q  = pc[j];
                float4 vq = *(const float4*)&lds[BV + r * 36 + 4 * j];
                cr += (double)vq.x * q.x + (double)vq.y * q.y
                    + (double)vq.z * q.z + (double)vq.w * q.w;
            }
            float cross32 = (float)cr;
            float dme;
            {
#pragma clang fp contract(off)
                dme = (vsq32 - 2.0f * cross32) + csqA[cand];
            }
            float dot_ = __shfl_xor(dme, 1, 64);
            int  candO = __shfl_xor(cand, 1, 64);
            bestC = ((dot_ < dme) || (dot_ == dme && candO < cand)) ? candO : cand;
        }

        if (u == 0) out[O_IDX + b * 8 + n] = (float)bestC;
        if (n == kchart) kcode = bestC;

        const float wn = __shfl(w_reg, (tid & 48) | n, 64);
        const float* pz = cbn + bestC * LT;     // exact fp32 code row (L2-hot)

        // own-quad z_q -> delta, loss (half-gated), blend accumulators
        {
            float4 zq = *(const float4*)(pz + 4 * sq);
            float4 d4;
            d4.x = vs.x - zq.x; d4.y = vs.y - zq.y;
            d4.z = vs.z - zq.z; d4.w = vs.w - zq.w;
            if (u < 8)
                lossAcc += wn * (d4.x * d4.x + d4.y * d4.y + d4.z * d4.z + d4.w * d4.w);
            zqb.x += wn * zq.x; zqb.y += wn * zq.y;
            zqb.z += wn * zq.z; zqb.w += wn * zq.w;
        }

        // s-net layer 1: lane u computes output j=u (delta on the fly)
        float s1;
        {
            float a0 = lds[BB1 + u];
#pragma unroll
            for (int q = 0; q < 8; ++q) {
                float4 zq = *(const float4*)(pz + 4 * q);
                float4 vq = *(const float4*)&lds[BV + r * 36 + 4 * q];
                float4 dq;
                dq.x = vq.x - zq.x; dq.y = vq.y - zq.y;
                dq.z = vq.z - zq.z; dq.w = vq.w - zq.w;
                float4 u0 = *(const float4*)&lds[BW1 + u * 36 + 4 * q];
                a0 += dot4(dq, u0);
            }
            s1 = gelu_f(a0);
        }

        // s-net layer 2: s1 shared via shuffles (j ascending 0..15 = original order)
        float4 zna = *(const float4*)&lds[BB2 + 4 * sq];
        {
            const int base = tid & 48;
#pragma unroll
            for (int j = 0; j < 16; ++j) {
                float sj = __shfl(s1, base | j, 64);
                float4 wj = *(const float4*)&lds[BW2T + j * 36 + 4 * sq];
                zna.x += sj * wj.x; zna.y += sj * wj.y;
                zna.z += sj * wj.z; zna.w += sj * wj.w;
            }
        }
        zn4.x += wn * zna.x; zn4.y += wn * zna.y;
        zn4.z += wn * zna.z; zn4.w += wn * zna.w;
        if (u < 8) *(float4*)&out[O_ZNALL + (b * 8 + n) * 32 + 4 * sq] = zna;
    }

    // ---- final per-row outputs ----
    if (u < 8) {
        float4 zt, zg;
        zt.x = (vs.x - zqb.x) - zn4.x; zt.y = (vs.y - zqb.y) - zn4.y;
        zt.z = (vs.z - zqb.z) - zn4.z; zt.w = (vs.w - zqb.w) - zn4.w;
        zg.x = zqb.x + zn4.x; zg.y = zqb.y + zn4.y;
        zg.z = zqb.z + zn4.z; zg.w = zqb.w + zn4.w;
        *(float4*)&out[O_ZN   + b * 32 + 4 * sq] = zn4;
        *(float4*)&out[O_ZTEX + b * 32 + 4 * sq] = zt;
        *(float4*)&out[O_ZGEO + b * 32 + 4 * sq] = zg;
        if (u == 0) out[O_KCODE + b] = (float)kcode;
    }

    // ---- block loss partial ----
#pragma unroll
    for (int off = 1; off < 64; off <<= 1) lossAcc += __shfl_xor(lossAcc, off, 64);
    __syncthreads();
    if ((tid & 63) == 0) lds[BMISC + (tid >> 6)] = lossAcc;
    __syncthreads();
    if (tid == 0)
        wspart[bid] = lds[BMISC] + lds[BMISC+1] + lds[BMISC+2] + lds[BMISC+3];
}

// ---------- finalize vq_loss ----------
__global__ __launch_bounds__(256) void fin_kernel(const float* __restrict__ wspart,
                                                  float* __restrict__ out)
{
    const int t = threadIdx.x;
    float sum = 0.f;
    for (int i = t; i < NBLK; i += 256) sum += wspart[i];
#pragma unroll
    for (int off = 1; off < 64; off <<= 1) sum += __shfl_xor(sum, off, 64);
    __shared__ float red[4];
    if ((t & 63) == 0) red[t >> 6] = sum;
    __syncthreads();
    if (t == 0)
        out[O_VQ] = (red[0] + red[1] + red[2] + red[3]) * (1.25f / (32768.0f * 32.0f));
}

extern "C" void kernel_launch(void* const* d_in, const int* in_sizes, int n_in,
                              void* d_out, int out_size, void* d_ws, size_t ws_size,
                              hipStream_t stream)
{
    const float* x   = (const float*)d_in[0];
    const float* W1  = (const float*)d_in[1];
    const float* b1  = (const float*)d_in[2];
    const float* W2  = (const float*)d_in[3];
    const float* b2  = (const float*)d_in[4];
    const float* Wk  = (const float*)d_in[5];
    const float* bk  = (const float*)d_in[6];
    const float* cq  = (const float*)d_in[7];
    const float* Wv  = (const float*)d_in[8];
    const float* bv  = (const float*)d_in[9];
    const float* cb  = (const float*)d_in[10];
    const float* Ws1 = (const float*)d_in[11];
    const float* bs1 = (const float*)d_in[12];
    const float* Ws2 = (const float*)d_in[13];
    const float* bs2 = (const float*)d_in[14];
    float* out = (float*)d_out;
    float* ws  = (float*)d_ws;

    prep_kernel<<<16, 256, 0, stream>>>(Wk, bk, cq, cb, ws);
    main_kernel<<<NBLK, 256, 0, stream>>>(x, W1, b1, W2, b2, Wv, bv, ws, out);
    chart_kernel<<<NBLK, 256, 0, stream>>>(cb, Ws1, bs1, Ws2, bs2, ws, out, ws + WS_PART);
    fin_kernel<<<1, 256, 0, stream>>>(ws + WS_PART, out);
}